// Round 1
// baseline (173.189 us; speedup 1.0000x reference)
//
#include <hip/hip_runtime.h>
#include <math.h>
#include <stdint.h>

#define NRAYS 8000
#define NB 2
#define GX 200
#define GY 200
#define GZ 16
#define BGRID (GX*GY*GZ)
#define NCH 18
#define FREE_ID 17
#define NTHREADS (NB*NRAYS)
#define BLOCK 256
#define NBLOCKS ((NTHREADS + BLOCK - 1)/BLOCK)

// ---------------- host: replicate _ray_constants() exactly ----------------
namespace {

struct MT19937 {
  uint32_t mt[624]; int mti;
  void seed(uint32_t s){
    mt[0]=s;
    for (mti=1; mti<624; ++mti)
      mt[mti] = 1812433253u*(mt[mti-1]^(mt[mti-1]>>30)) + (uint32_t)mti;
  }
  uint32_t next(){
    if (mti >= 624){
      for (int i=0;i<624;i++){
        uint32_t y = (mt[i]&0x80000000u) | (mt[(i+1)%624]&0x7fffffffu);
        mt[i] = mt[(i+397)%624] ^ (y>>1) ^ ((y&1u)? 2567483615u : 0u);
      }
      mti = 0;
    }
    uint32_t y = mt[mti++];
    y ^= y>>11; y ^= (y<<7)&2636928640u; y ^= (y<<15)&4022730752u; y ^= y>>18;
    return y;
  }
};

// numpy random_interval: masked rejection on 32-bit draws, result in [0, mx]
static uint32_t rinterval(MT19937& g, uint32_t mx){
  if (mx==0) return 0;
  uint32_t mask=mx; mask|=mask>>1; mask|=mask>>2; mask|=mask>>4; mask|=mask>>8; mask|=mask>>16;
  uint32_t v;
  do { v = g.next()&mask; } while (v>mx);
  return v;
}

// returns s_max; fills out[NRAYS] with (dx,dy,dz,dt)
static int build_table(float4* out){
  double pitch[128]; int npi=0;
  for (int k=0;k<10;k++) pitch[npi++] = -(M_PI/2.0 - atan((double)(k+1)));
  while (pitch[npi-1] < 0.21){
    double d = pitch[npi-1]-pitch[npi-2];
    pitch[npi] = pitch[npi-1]+d; ++npi;
  }
  int nrays = npi*360;   // expected 39*360 = 14040
  static float rx[128*360], ry[128*360], rz[128*360], rdt[128*360];
  float dtmin = 1e30f;
  for (int p=0;p<npi;p++){
    double cp = cos(pitch[p]), sp = sin(pitch[p]);
    for (int a=0;a<360;a++){
      double az = (double)a * (M_PI/180.0);   // math.radians
      int i = p*360+a;
      rx[i]=(float)(cp*cos(az)); ry[i]=(float)(cp*sin(az)); rz[i]=(float)sp;
      float ma = fmaxf(fabsf(rx[i]), fmaxf(fabsf(ry[i]), fabsf(rz[i])));
      ma = ma + 1e-8f;                         // float32 add, matches numpy NEP50
      rdt[i] = 0.4f/ma;                        // float32 divide
      if (rdt[i] < dtmin) dtmin = rdt[i];
    }
  }
  int smax = (int)fmin(ceil(60.0/(double)dtmin), 512.0);
  // RandomState(0).permutation(nrays)[:NRAYS]  (Fisher-Yates, j in [0,i])
  static int perm[128*360];
  for (int i=0;i<nrays;i++) perm[i]=i;
  MT19937 g; g.seed(0);
  for (int i=nrays-1;i>=1;--i){
    uint32_t j = rinterval(g, (uint32_t)i);
    int tmp = perm[i]; perm[i]=perm[j]; perm[j]=tmp;
  }
  for (int i=0;i<NRAYS;i++){
    int id = perm[i];
    out[i] = make_float4(rx[id], ry[id], rz[id], rdt[id]);
  }
  return smax;
}

} // namespace

// ---------------- device ----------------

__device__ inline float lse18(const float* __restrict__ lg, float& mx_out){
  float mx = lg[0];
  #pragma unroll
  for (int c=1;c<NCH;c++) mx = fmaxf(mx, lg[c]);
  float s = 0.f;
  #pragma unroll
  for (int c=0;c<NCH;c++) s += expf(lg[c]-mx);
  mx_out = mx;
  return logf(s);
}

__global__ __launch_bounds__(BLOCK) void ray_loss_kernel(
    const float* __restrict__ logits, const float* __restrict__ origins,
    const int* __restrict__ sem, const int* __restrict__ cam,
    const float4* __restrict__ rays, double* __restrict__ partials, int S)
{
  // per-thread stats: [b][5] = {n_pre, sum_pre, n_ray, sum_hit, sum_ce}
  float v[10];
  #pragma unroll
  for (int j=0;j<10;j++) v[j] = 0.f;

  int gid = blockIdx.x*BLOCK + threadIdx.x;
  if (gid < NTHREADS){
    int b = (gid >= NRAYS) ? 1 : 0;
    int r = gid - b*NRAYS;
    float ox=origins[b*3+0], oy=origins[b*3+1], oz=origins[b*3+2];
    float4 rd = rays[r];

    // phase 1: find first occupied step (early exit)
    int hit=-1, hitflat=0, hitgt=0;
    for (int s=0;s<S;++s){
      float t = __fmul_rn(rd.w, (float)s + 0.5f);
      if (t > 60.0f) break;                   // t strictly increasing
      float px = __fadd_rn(ox, __fmul_rn(rd.x, t));
      float py = __fadd_rn(oy, __fmul_rn(rd.y, t));
      float pz = __fadd_rn(oz, __fmul_rn(rd.z, t));
      int vx = (int)floorf(__fdiv_rn(__fadd_rn(px, 40.0f), 0.4f));
      int vy = (int)floorf(__fdiv_rn(__fadd_rn(py, 40.0f), 0.4f));
      int vz = (int)floorf(__fdiv_rn(__fadd_rn(pz, 1.0f), 0.4f));
      if (((unsigned)vx >= (unsigned)GX) | ((unsigned)vy >= (unsigned)GY) |
          ((unsigned)vz >= (unsigned)GZ)) continue;
      int flat = (vx*GY+vy)*GZ+vz;
      int gt = sem[b*BGRID+flat];
      if (gt != FREE_ID){ hit=s; hitflat=flat; hitgt=gt; break; }
    }

    if (hit >= 0 && cam[b*BGRID+hitflat] > 0){   // ray_valid
      const float* lg = logits + ((size_t)(b*BGRID+hitflat))*NCH;
      float mx; float ls = lse18(lg, mx);
      float pf = expf((lg[FREE_ID]-mx) - ls);         // p_free at hit
      float bh = -logf(fmaxf(1.0f - pf, 1e-6f));      // bce_hit
      float ce = -((lg[hitgt]-mx) - ls);              // ce_hit
      int base = b*5;
      v[base+2]=1.f; v[base+3]=bh; v[base+4]=ce;

      // phase 2: pre-hit free-space BCE (steps < hit, in-bounds only)
      float npre=0.f, spre=0.f;
      for (int s=0;s<hit;++s){
        float t = __fmul_rn(rd.w, (float)s + 0.5f);
        float px = __fadd_rn(ox, __fmul_rn(rd.x, t));
        float py = __fadd_rn(oy, __fmul_rn(rd.y, t));
        float pz = __fadd_rn(oz, __fmul_rn(rd.z, t));
        int vx = (int)floorf(__fdiv_rn(__fadd_rn(px, 40.0f), 0.4f));
        int vy = (int)floorf(__fdiv_rn(__fadd_rn(py, 40.0f), 0.4f));
        int vz = (int)floorf(__fdiv_rn(__fadd_rn(pz, 1.0f), 0.4f));
        if (((unsigned)vx >= (unsigned)GX) | ((unsigned)vy >= (unsigned)GY) |
            ((unsigned)vz >= (unsigned)GZ)) continue;
        int flat = (vx*GY+vy)*GZ+vz;
        const float* lg2 = logits + ((size_t)(b*BGRID+flat))*NCH;
        float mx2; float ls2 = lse18(lg2, mx2);
        float pf2 = expf((lg2[FREE_ID]-mx2) - ls2);
        spre += -logf(fmaxf(pf2, 1e-6f));
        npre += 1.f;
      }
      v[base+0]=npre; v[base+1]=spre;
    }
  }

  // wave reduce (64-lane) then cross-wave via LDS, one double partial row/block
  #pragma unroll
  for (int j=0;j<10;j++){
    for (int off=32; off>=1; off>>=1) v[j] += __shfl_down(v[j], off);
  }
  __shared__ float red[BLOCK/64][10];
  int wv = threadIdx.x>>6, ln = threadIdx.x&63;
  if (ln==0){
    #pragma unroll
    for (int j=0;j<10;j++) red[wv][j]=v[j];
  }
  __syncthreads();
  if (threadIdx.x==0){
    #pragma unroll
    for (int j=0;j<10;j++){
      double s = (double)red[0][j]+(double)red[1][j]+(double)red[2][j]+(double)red[3][j];
      partials[(size_t)blockIdx.x*10+j] = s;
    }
  }
}

__global__ void finalize_kernel(const double* __restrict__ partials,
                                float* __restrict__ out, int nblocks)
{
  if (threadIdx.x!=0 || blockIdx.x!=0) return;
  double acc[10];
  for (int j=0;j<10;j++) acc[j]=0.0;
  for (int k=0;k<nblocks;k++)
    for (int j=0;j<10;j++) acc[j]+=partials[(size_t)k*10+j];
  double sp=0, cp=0, sh=0, sc=0, ch=0;
  for (int b=0;b<NB;b++){
    double n_pre=acc[b*5+0], s_pre=acc[b*5+1];
    double n_ray=acc[b*5+2], s_hit=acc[b*5+3], s_ce=acc[b*5+4];
    if (n_pre>0.0){ sp += s_pre/n_pre; cp+=1.0; }
    if (n_ray>0.0){ sh += s_hit/n_ray; sc += s_ce/n_ray; ch+=1.0; }
  }
  double lp = sp / (cp>0.0?cp:1.0);
  double lh = sh / (ch>0.0?ch:1.0);
  double lc = sc / (ch>0.0?ch:1.0);
  out[0] = (float)(lp+lh+lc);
}

extern "C" void kernel_launch(void* const* d_in, const int* in_sizes, int n_in,
                              void* d_out, int out_size, void* d_ws, size_t ws_size,
                              hipStream_t stream)
{
  (void)in_sizes; (void)n_in; (void)out_size; (void)ws_size;
  const float* logits  = (const float*)d_in[0];
  const float* origins = (const float*)d_in[1];
  const int*   sem     = (const int*)d_in[2];
  const int*   cam     = (const int*)d_in[3];
  float* out = (float*)d_out;

  // Rebuilt every call (deterministic); static so the graph's H2D memcpy node
  // has a stable host address across replays.
  static float4 h_tab[NRAYS];
  int smax = build_table(h_tab);

  double* partials = (double*)d_ws;                       // NBLOCKS*10 doubles (5040 B)
  float4* d_tab = (float4*)((char*)d_ws + 8192);          // 128 KB ray table
  hipMemcpyAsync(d_tab, h_tab, sizeof(float4)*NRAYS, hipMemcpyHostToDevice, stream);

  ray_loss_kernel<<<NBLOCKS, BLOCK, 0, stream>>>(logits, origins, sem, cam,
                                                 d_tab, partials, smax);
  finalize_kernel<<<1, 64, 0, stream>>>(partials, out, NBLOCKS);
}

// Round 2
// 29.673 us; speedup vs baseline: 5.8366x; 5.8366x over previous
//
#include <hip/hip_runtime.h>
#include <math.h>
#include <stdint.h>

#define NRAYS 8000
#define NB 2
#define GX 200
#define GY 200
#define GZ 16
#define BGRID (GX*GY*GZ)
#define NCH 18
#define FREE_ID 17
#define NWAVES (NB*NRAYS)
#define BLOCK 1024
#define WPB (BLOCK/64)
#define NBLOCKS (NWAVES/WPB)   // 1000
#define RBLOCK 256

// ---------------- host: replicate _ray_constants() exactly ----------------
namespace {

struct MT19937 {
  uint32_t mt[624]; int mti;
  void seed(uint32_t s){
    mt[0]=s;
    for (mti=1; mti<624; ++mti)
      mt[mti] = 1812433253u*(mt[mti-1]^(mt[mti-1]>>30)) + (uint32_t)mti;
  }
  uint32_t next(){
    if (mti >= 624){
      for (int i=0;i<624;i++){
        uint32_t y = (mt[i]&0x80000000u) | (mt[(i+1)%624]&0x7fffffffu);
        mt[i] = mt[(i+397)%624] ^ (y>>1) ^ ((y&1u)? 2567483615u : 0u);
      }
      mti = 0;
    }
    uint32_t y = mt[mti++];
    y ^= y>>11; y ^= (y<<7)&2636928640u; y ^= (y<<15)&4022730752u; y ^= y>>18;
    return y;
  }
};

static uint32_t rinterval(MT19937& g, uint32_t mx){
  if (mx==0) return 0;
  uint32_t mask=mx; mask|=mask>>1; mask|=mask>>2; mask|=mask>>4; mask|=mask>>8; mask|=mask>>16;
  uint32_t v;
  do { v = g.next()&mask; } while (v>mx);
  return v;
}

static int build_table(float4* out){
  double pitch[128]; int npi=0;
  for (int k=0;k<10;k++) pitch[npi++] = -(M_PI/2.0 - atan((double)(k+1)));
  while (pitch[npi-1] < 0.21){
    double d = pitch[npi-1]-pitch[npi-2];
    pitch[npi] = pitch[npi-1]+d; ++npi;
  }
  int nrays = npi*360;   // 39*360 = 14040
  static float rx[128*360], ry[128*360], rz[128*360], rdt[128*360];
  float dtmin = 1e30f;
  for (int p=0;p<npi;p++){
    double cp = cos(pitch[p]), sp = sin(pitch[p]);
    for (int a=0;a<360;a++){
      double az = (double)a * (M_PI/180.0);
      int i = p*360+a;
      rx[i]=(float)(cp*cos(az)); ry[i]=(float)(cp*sin(az)); rz[i]=(float)sp;
      float ma = fmaxf(fabsf(rx[i]), fmaxf(fabsf(ry[i]), fabsf(rz[i])));
      ma = ma + 1e-8f;
      rdt[i] = 0.4f/ma;
      if (rdt[i] < dtmin) dtmin = rdt[i];
    }
  }
  int smax = (int)fmin(ceil(60.0/(double)dtmin), 512.0);
  static int perm[128*360];
  for (int i=0;i<nrays;i++) perm[i]=i;
  MT19937 g; g.seed(0);
  for (int i=nrays-1;i>=1;--i){
    uint32_t j = rinterval(g, (uint32_t)i);
    int tmp = perm[i]; perm[i]=perm[j]; perm[j]=tmp;
  }
  for (int i=0;i<NRAYS;i++){
    int id = perm[i];
    out[i] = make_float4(rx[id], ry[id], rz[id], rdt[id]);
  }
  return smax;
}

// Pinned (DMA-capable) constant ray table, built once at library load —
// input-independent, so every kernel_launch call does identical work.
struct TabHolder {
  float4* h; int smax;
  TabHolder(){
    h = nullptr;
    hipError_t e = hipHostMalloc((void**)&h, sizeof(float4)*NRAYS, 0);
    if (e != hipSuccess || !h){ static float4 fb[NRAYS]; h = fb; }
    smax = build_table(h);
  }
};
static TabHolder g_tab;

} // namespace

// ---------------- device ----------------

// step geometry: returns in-bounds-and-valid flag + flat index
__device__ inline bool probe(float ox,float oy,float oz,const float4& rd,
                             int s,int S,int& flat)
{
  float t = __fmul_rn(rd.w, (float)s + 0.5f);
  bool tok = (s < S) && (t <= 60.0f);
  float px = __fadd_rn(ox, __fmul_rn(rd.x, t));
  float py = __fadd_rn(oy, __fmul_rn(rd.y, t));
  float pz = __fadd_rn(oz, __fmul_rn(rd.z, t));
  int vx = (int)floorf(__fdiv_rn(__fadd_rn(px, 40.0f), 0.4f));
  int vy = (int)floorf(__fdiv_rn(__fadd_rn(py, 40.0f), 0.4f));
  int vz = (int)floorf(__fdiv_rn(__fadd_rn(pz, 1.0f), 0.4f));
  flat = (vx*GY+vy)*GZ+vz;
  return tok & ((unsigned)vx < (unsigned)GX) & ((unsigned)vy < (unsigned)GY)
             & ((unsigned)vz < (unsigned)GZ);
}

__device__ inline void lse18(const float* __restrict__ lg, float& mx, float& ls){
  float m = lg[0];
  #pragma unroll
  for (int c=1;c<NCH;c++) m = fmaxf(m, lg[c]);
  float s = 0.f;
  #pragma unroll
  for (int c=0;c<NCH;c++) s += expf(lg[c]-m);
  mx = m; ls = logf(s);
}

__global__ __launch_bounds__(BLOCK) void ray_loss_kernel(
    const float* __restrict__ logits, const float* __restrict__ origins,
    const int* __restrict__ sem, const int* __restrict__ cam,
    const float4* __restrict__ rays, float* __restrict__ partials, int S)
{
  const int wv = threadIdx.x >> 6, lane = threadIdx.x & 63;
  const int wid = blockIdx.x * WPB + wv;            // ray id, 0..15999
  float v[10];
  #pragma unroll
  for (int j=0;j<10;j++) v[j] = 0.f;

  {
    const int b = (wid >= NRAYS) ? 1 : 0;
    const int r = wid - b*NRAYS;
    const float ox=origins[b*3+0], oy=origins[b*3+1], oz=origins[b*3+2];
    const float4 rd = rays[r];
    const int nchunks = (S + 63) >> 6;

    // pass 1: parallel first-hit scan, 64 steps per round
    int hit = 0x7fffffff, hitflat = 0, hitgt = 0;
    for (int c=0; c<nchunks; ++c){
      const int s = (c<<6) + lane;
      int flat;
      bool inb = probe(ox,oy,oz,rd,s,S,flat);
      int gt = FREE_ID;
      if (inb) gt = sem[b*BGRID+flat];
      unsigned long long m = __ballot(inb && (gt != FREE_ID));
      if (m){
        int f = __ffsll(m) - 1;
        hit = (c<<6) + f;
        hitflat = __shfl(flat, f);
        hitgt   = __shfl(gt, f);
        break;
      }
      // all lanes past range/max-dist -> later chunks can't contribute
      float tlast = __fmul_rn(rd.w, (float)((c<<6)+63) + 0.5f);
      if (((c<<6)+63 >= S-1) ? ((c+1)<<6) >= S : (tlast > 60.0f)) { /*fallthrough check*/ }
      if (__ballot((s < S) && (__fmul_rn(rd.w,(float)s+0.5f) <= 60.0f)) == 0ULL) break;
    }

    bool rv = false;
    if (hit != 0x7fffffff) rv = (cam[b*BGRID+hitflat] > 0);

    if (rv){
      // hit terms (uniform address -> broadcast loads)
      const float* lg = logits + (size_t)(b*BGRID+hitflat)*NCH;
      float mx, ls; lse18(lg, mx, ls);
      float pf = expf((lg[FREE_ID]-mx) - ls);
      float bh = -logf(fmaxf(1.0f - pf, 1e-6f));
      float ce = -((lg[hitgt]-mx) - ls);

      // pass 2: pre-hit free-space BCE, data-parallel over steps
      float npre = 0.f, spre = 0.f;
      const int hitc = hit >> 6;
      for (int c=0; c<=hitc; ++c){
        const int s = (c<<6) + lane;
        int flat;
        bool inb = probe(ox,oy,oz,rd,s,S,flat);
        if (inb && (s < hit)){
          const float* lg2 = logits + (size_t)(b*BGRID+flat)*NCH;
          float mx2, ls2; lse18(lg2, mx2, ls2);
          float pf2 = expf((lg2[FREE_ID]-mx2) - ls2);
          spre += -logf(fmaxf(pf2, 1e-6f));
          npre += 1.f;
        }
      }
      #pragma unroll
      for (int off=32; off>=1; off>>=1){
        npre += __shfl_down(npre, off);
        spre += __shfl_down(spre, off);
      }
      if (lane == 0){
        const int base = b*5;
        v[base+0]=npre; v[base+1]=spre; v[base+2]=1.f; v[base+3]=bh; v[base+4]=ce;
      }
    }
  }

  // block reduce: each wave's lane 0 writes its row; wave 0 sums in fixed order
  __shared__ float red[WPB][10];
  if (lane == 0){
    #pragma unroll
    for (int j=0;j<10;j++) red[wv][j] = v[j];
  }
  __syncthreads();
  if (wv == 0 && lane < 10){
    float s = 0.f;
    #pragma unroll
    for (int k=0;k<WPB;k++) s += red[k][lane];
    partials[(size_t)blockIdx.x*10 + lane] = s;
  }
}

__global__ __launch_bounds__(RBLOCK) void finalize_kernel(
    const float* __restrict__ partials, float* __restrict__ out, int nblocks)
{
  __shared__ double acc[RBLOCK][10];
  double a[10];
  #pragma unroll
  for (int j=0;j<10;j++) a[j]=0.0;
  for (int r = threadIdx.x; r < nblocks; r += RBLOCK){
    #pragma unroll
    for (int j=0;j<10;j++) a[j] += (double)partials[(size_t)r*10+j];
  }
  #pragma unroll
  for (int j=0;j<10;j++) acc[threadIdx.x][j]=a[j];
  __syncthreads();
  for (int off=RBLOCK/2; off>=1; off>>=1){
    if ((int)threadIdx.x < off){
      #pragma unroll
      for (int j=0;j<10;j++) acc[threadIdx.x][j]+=acc[threadIdx.x+off][j];
    }
    __syncthreads();
  }
  if (threadIdx.x==0){
    double sp=0, cp=0, sh=0, sc=0, ch=0;
    for (int b=0;b<NB;b++){
      double n_pre=acc[0][b*5+0], s_pre=acc[0][b*5+1];
      double n_ray=acc[0][b*5+2], s_hit=acc[0][b*5+3], s_ce=acc[0][b*5+4];
      if (n_pre>0.0){ sp += s_pre/n_pre; cp+=1.0; }
      if (n_ray>0.0){ sh += s_hit/n_ray; sc += s_ce/n_ray; ch+=1.0; }
    }
    double lp = sp / (cp>0.0?cp:1.0);
    double lh = sh / (ch>0.0?ch:1.0);
    double lc = sc / (ch>0.0?ch:1.0);
    out[0] = (float)(lp+lh+lc);
  }
}

extern "C" void kernel_launch(void* const* d_in, const int* in_sizes, int n_in,
                              void* d_out, int out_size, void* d_ws, size_t ws_size,
                              hipStream_t stream)
{
  (void)in_sizes; (void)n_in; (void)out_size; (void)ws_size;
  const float* logits  = (const float*)d_in[0];
  const float* origins = (const float*)d_in[1];
  const int*   sem     = (const int*)d_in[2];
  const int*   cam     = (const int*)d_in[3];
  float* out = (float*)d_out;

  float4* d_tab = (float4*)d_ws;                          // 128000 B
  float*  partials = (float*)((char*)d_ws + 131072);      // 1000*10 floats
  hipMemcpyAsync(d_tab, g_tab.h, sizeof(float4)*NRAYS,
                 hipMemcpyHostToDevice, stream);

  ray_loss_kernel<<<NBLOCKS, BLOCK, 0, stream>>>(logits, origins, sem, cam,
                                                 d_tab, partials, g_tab.smax);
  finalize_kernel<<<1, RBLOCK, 0, stream>>>(partials, out, NBLOCKS);
}